// Round 3
// baseline (451.289 us; speedup 1.0000x reference)
//
#include <hip/hip_runtime.h>

// Problem constants (fixed by the reference: B=4, S=2048, D_IN=D_OUT=4096)
#define GM 8192
#define GN 4096
#define GK 4096
#define NT (GK / 64)

// Workspace layout (bytes)
#define QX_OFF   0ull                      // int8 [8192][4096] = 33.5 MB; first 24 KB
                                           // doubles as minmax partials (consumed by
                                           // k_params BEFORE k_quant overwrites it)
#define QW_OFF   33554432ull               // int8 [4096][4096]  = 16.8 MB
#define RSX_OFF  50331648ull               // int32[8192]
#define RSW_OFF  50364416ull               // int32[4096]
#define PRM_OFF  50380832ull               // params: sx, zxf, sw, zwf, sxsw, zxi, zwi

#define MMB_X 2048                         // minmax blocks for x
#define MMB_W 1024                         // minmax blocks for W

using v4i  = __attribute__((ext_vector_type(4)))  int;
using v16i = __attribute__((ext_vector_type(16))) int;

// ---------- helpers ----------
__device__ __forceinline__ void async16(const signed char* g, signed char* l) {
    // 16B per lane, LDS dest = wave-uniform base + lane*16 (m104/m108 rule)
    __builtin_amdgcn_global_load_lds((const __attribute__((address_space(1))) void*)g,
                                     (__attribute__((address_space(3))) void*)l,
                                     16, 0, 0);
}

// ---------- kernels ----------
// Per-block partial min/max, plain stores (atomics removed in r1: -77 us).
// part[]: [0,2048) mx_x | [2048,4096) mn_x | [4096,5120) mx_w | [5120,6144) mn_w
__global__ void k_minmax(const float4* __restrict__ x, const float4* __restrict__ Wt,
                         float* __restrict__ part) {
    const float4* p; int n4, b0, nb; float* dst;
    if (blockIdx.x < MMB_X) { p = x;  n4 = GM * GK / 4; b0 = blockIdx.x;         nb = MMB_X; dst = part;        }
    else                    { p = Wt; n4 = GN * GK / 4; b0 = blockIdx.x - MMB_X; nb = MMB_W; dst = part + 4096; }
    float mx = -3.4e38f, mn = 3.4e38f;
    for (int i = b0 * 256 + threadIdx.x; i < n4; i += nb * 256) {
        float4 v = p[i];
        mx = fmaxf(mx, fmaxf(fmaxf(v.x, v.y), fmaxf(v.z, v.w)));
        mn = fminf(mn, fminf(fminf(v.x, v.y), fminf(v.z, v.w)));
    }
    #pragma unroll
    for (int o = 32; o > 0; o >>= 1) {
        mx = fmaxf(mx, __shfl_down(mx, o));
        mn = fminf(mn, __shfl_down(mn, o));
    }
    __shared__ float smx[4], smn[4];
    int w = threadIdx.x >> 6;
    if ((threadIdx.x & 63) == 0) { smx[w] = mx; smn[w] = mn; }
    __syncthreads();
    if (threadIdx.x == 0) {
        #pragma unroll
        for (int i = 1; i < 4; i++) { mx = fmaxf(mx, smx[i]); mn = fminf(mn, smn[i]); }
        dst[b0]      = mx;
        dst[nb + b0] = mn;
    }
}

// Reduce the 6144 partials (24 KB, L2-hot) and emit quant params. One block.
__global__ void k_params(const float* __restrict__ part, float* prm) {
    const int t = threadIdx.x;
    float v0 = -3.4e38f, v1 = 3.4e38f, v2 = -3.4e38f, v3 = 3.4e38f;
    for (int i = t; i < MMB_X; i += 256) {
        v0 = fmaxf(v0, part[i]);
        v1 = fminf(v1, part[MMB_X + i]);
    }
    for (int i = t; i < MMB_W; i += 256) {
        v2 = fmaxf(v2, part[4096 + i]);
        v3 = fminf(v3, part[5120 + i]);
    }
    #pragma unroll
    for (int o = 32; o > 0; o >>= 1) {
        v0 = fmaxf(v0, __shfl_down(v0, o));
        v1 = fminf(v1, __shfl_down(v1, o));
        v2 = fmaxf(v2, __shfl_down(v2, o));
        v3 = fminf(v3, __shfl_down(v3, o));
    }
    __shared__ float s[4][4];
    const int wv = t >> 6;
    if ((t & 63) == 0) { s[wv][0] = v0; s[wv][1] = v1; s[wv][2] = v2; s[wv][3] = v3; }
    __syncthreads();
    if (t == 0) {
        #pragma unroll
        for (int i = 1; i < 4; i++) {
            v0 = fmaxf(v0, s[i][0]); v1 = fminf(v1, s[i][1]);
            v2 = fmaxf(v2, s[i][2]); v3 = fminf(v3, s[i][3]);
        }
        float sx  = (v0 - v1) / 255.0f;
        float zxf = rintf(-128.0f - v1 / sx);
        float sw  = (v2 - v3) / 255.0f;
        float zwf = rintf(-128.0f - v3 / sw);
        prm[0] = sx; prm[1] = zxf; prm[2] = sw; prm[3] = zwf; prm[4] = sx * sw;
        int* ip = (int*)prm;
        ip[5] = (int)zxf; ip[6] = (int)zwf;
    }
}

// ONE WAVE per row of 4096 floats (was: one block/row): no __syncthreads, no LDS
// reduce, 16 independent float4 loads in flight per lane. Quant math unchanged
// (exact fp32 division to match JAX rounding; rcp-mul would flip ~6e3 quants).
// waves [0,GM) -> x rows; [GM, GM+GN) -> W rows.  grid = (GM+GN)/4 blocks.
__global__ void k_quant(const float* __restrict__ x, const float* __restrict__ Wt,
                        signed char* __restrict__ qx, signed char* __restrict__ qw,
                        int* __restrict__ rsx, int* __restrict__ rsw,
                        const float* __restrict__ prm) {
    const int wid  = (blockIdx.x << 2) | (threadIdx.x >> 6);   // global wave id
    const int lane = threadIdx.x & 63;
    const float* src; signed char* q; int* rs; int pidx, row;
    if (wid < GM) { row = wid;      src = x;  q = qx; rs = rsx; pidx = 0; }
    else          { row = wid - GM; src = Wt; q = qw; rs = rsw; pidx = 2; }
    const float s  = prm[pidx];
    const float zp = prm[pidx + 1];
    const float4* srow = (const float4*)(src + (size_t)row * GK);
    int* qrow = (int*)(q + (size_t)row * GK);
    int acc = 0;
    #pragma unroll
    for (int i = 0; i < 16; i++) {
        float4 v = srow[i * 64 + lane];
        int q0 = (int)fminf(fmaxf(rintf(v.x / s) + zp, -128.0f), 127.0f);
        int q1 = (int)fminf(fmaxf(rintf(v.y / s) + zp, -128.0f), 127.0f);
        int q2 = (int)fminf(fmaxf(rintf(v.z / s) + zp, -128.0f), 127.0f);
        int q3 = (int)fminf(fmaxf(rintf(v.w / s) + zp, -128.0f), 127.0f);
        acc += q0 + q1 + q2 + q3;
        qrow[i * 64 + lane] = (q0 & 255) | ((q1 & 255) << 8) | ((q2 & 255) << 16)
                            | ((q3 & 255) << 24);
    }
    #pragma unroll
    for (int o = 32; o > 0; o >>= 1) acc += __shfl_down(acc, o);
    if (lane == 0) rs[row] = acc;
}

// 256x128 C-tile, 256 threads (4 waves, 2M x 2N of 128x64 wave-tiles), BK=64,
// 3 LDS buffers (72 KB) -> 2 BLOCKS/CU. Same per-wave structure as r1 (12
// ds_read_b128 : 16 MFMA, ratio 0.75) and same counted-vmcnt distance-2
// pipeline, but two independent barrier domains per CU: r2's counters showed
// nothing saturated (MFMA pipe ~12% busy, LDS ~20%, VALU 19%) -> stall-bound
// from ONE lockstep barrier domain. Cross-block overlap (m114) hides it.
// r2's hand-pinned phase split regressed (150->157); compute stays monolithic.
__global__ __launch_bounds__(256, 2) void k_gemm(
    const signed char* __restrict__ qx, const signed char* __restrict__ qw,
    const int* __restrict__ rsx, const int* __restrict__ rsw,
    const float* __restrict__ bias, const float* __restrict__ prm,
    float* __restrict__ out) {
    __shared__ __align__(16) signed char lds[3][24576];  // A[256][64] | B[128][64]

    const int tid  = threadIdx.x;
    const int lane = tid & 63;
    const int w    = tid >> 6;          // 0..3
    // chunked XCD swizzle (1024 blocks, %8==0 -> bijective): consecutive orig
    // bids (sharing an A-panel via m-major mapping) land on one XCD's L2.
    const int bid  = ((blockIdx.x & 7) << 7) | (blockIdx.x >> 3);
    const int tm0  = (bid >> 5) * 256;  // 32 M-tiles
    const int tn0  = (bid & 31) * 128;  // 32 N-tiles

    // ---- staging: 24 x 1KB segments (16 A + 8 B); wave w -> segs [6w, 6w+6) ----
    // dest is linear (lane*16); source chunk pre-swizzled so reads can apply the
    // same XOR (rule #21: inverse-swz source + swz read, LDS stays linear).
    const int sr = lane >> 2;                              // row 0..15 in segment
    const int sc = ((lane & 3) ^ ((lane >> 3) & 3)) * 16;  // = (lane&3)^((sr>>1)&3)
    const signed char* gsg[6];
    int lof[6];
    #pragma unroll
    for (int j6 = 0; j6 < 6; j6++) {
        const int j = w * 6 + j6;
        if (j < 16) { gsg[j6] = qx + (size_t)(tm0 + 16 * j        + sr) * GK + sc; lof[j6] = j * 1024; }
        else        { gsg[j6] = qw + (size_t)(tn0 + 16 * (j - 16) + sr) * GK + sc; lof[j6] = 16384 + (j - 16) * 1024; }
    }

    // ---- fragment / MFMA setup ----
    const int wr = w >> 1;              // 0..1 : wave row (M)
    const int wc = w & 1;               // 0..1 : wave col (N)
    const int fr = lane & 31;
    const int fh = lane >> 5;

    v16i acc[4][2] = {};

    auto STAGE = [&](int buf, int kt) {
        #pragma unroll
        for (int j6 = 0; j6 < 6; j6++)
            async16(gsg[j6] + (size_t)kt * 64, &lds[buf][lof[j6]]);
    };
    auto COMPUTE = [&](int rdi) {
        const signed char* cA = lds[rdi];
        const signed char* cB = lds[rdi] + 16384;
        #pragma unroll
        for (int s = 0; s < 2; s++) {
            const int cc = s * 2 + fh;                    // 16B chunk index 0..3
            const int ca = (cc ^ ((fr >> 1) & 3)) * 16;   // conflict-free swizzle
            v4i a0 = *(const v4i*)(cA + (wr * 128      + fr) * 64 + ca);
            v4i a1 = *(const v4i*)(cA + (wr * 128 + 32 + fr) * 64 + ca);
            v4i a2 = *(const v4i*)(cA + (wr * 128 + 64 + fr) * 64 + ca);
            v4i a3 = *(const v4i*)(cA + (wr * 128 + 96 + fr) * 64 + ca);
            v4i b0 = *(const v4i*)(cB + (wc * 64       + fr) * 64 + ca);
            v4i b1 = *(const v4i*)(cB + (wc * 64  + 32 + fr) * 64 + ca);
            acc[0][0] = __builtin_amdgcn_mfma_i32_32x32x32_i8(a0, b0, acc[0][0], 0, 0, 0);
            acc[0][1] = __builtin_amdgcn_mfma_i32_32x32x32_i8(a0, b1, acc[0][1], 0, 0, 0);
            acc[1][0] = __builtin_amdgcn_mfma_i32_32x32x32_i8(a1, b0, acc[1][0], 0, 0, 0);
            acc[1][1] = __builtin_amdgcn_mfma_i32_32x32x32_i8(a1, b1, acc[1][1], 0, 0, 0);
            acc[2][0] = __builtin_amdgcn_mfma_i32_32x32x32_i8(a2, b0, acc[2][0], 0, 0, 0);
            acc[2][1] = __builtin_amdgcn_mfma_i32_32x32x32_i8(a2, b1, acc[2][1], 0, 0, 0);
            acc[3][0] = __builtin_amdgcn_mfma_i32_32x32x32_i8(a3, b0, acc[3][0], 0, 0, 0);
            acc[3][1] = __builtin_amdgcn_mfma_i32_32x32x32_i8(a3, b1, acc[3][1], 0, 0, 0);
        }
    };

    // prologue: stage kt=0 -> buf0, kt=1 -> buf1 (12 loads in flight per wave)
    STAGE(0, 0);
    STAGE(1, 1);
    asm volatile("s_waitcnt vmcnt(6)" ::: "memory");   // buf0's 6 retired
    __builtin_amdgcn_s_barrier();                      // publish buf0

    // steady state: [stage kt+2 | compute kt | vmcnt(6) retiring buf kt+1 | barrier]
    // Overwrite of buf kt+2 (== kt-1 mod 3) is safe: every wave's reads of that
    // buffer were consumed by MFMAs (compiler lgkm waits) before the prior barrier.
    int rd = 0;
    for (int kt = 0; kt < NT - 2; ++kt) {
        int st = rd + 2; if (st >= 3) st -= 3;
        STAGE(st, kt + 2);
        COMPUTE(rd);
        asm volatile("s_waitcnt vmcnt(6)" ::: "memory");
        __builtin_amdgcn_s_barrier();
        rd = (rd + 1 == 3) ? 0 : rd + 1;
    }
    // kt = NT-2: buf NT-1 (6 loads) still in flight
    COMPUTE(rd);
    asm volatile("s_waitcnt vmcnt(0)" ::: "memory");
    __builtin_amdgcn_s_barrier();
    rd = (rd + 1 == 3) ? 0 : rd + 1;
    // kt = NT-1
    COMPUTE(rd);

    // epilogue: acc - zw*rowsum_x[m] - zx*rowsum_w[n] + K*zx*zw, scale, +bias
    // 32x32 C/D: col = lane&31, row = (reg&3) + 8*(reg>>2) + 4*(lane>>5)
    const float sxsw = prm[4];
    const int* ip = (const int*)prm;
    const int zxi = ip[5], zwi = ip[6];
    const int kzz = GK * zxi * zwi;
    #pragma unroll
    for (int i = 0; i < 4; i++) {
        #pragma unroll
        for (int j = 0; j < 2; j++) {
            const int col = tn0 + wc * 64 + j * 32 + fr;
            const int ccol = kzz - zxi * rsw[col];
            const float bv = bias[col];
            #pragma unroll
            for (int reg = 0; reg < 16; reg++) {
                const int row = tm0 + wr * 128 + i * 32
                              + (reg & 3) + 8 * (reg >> 2) + 4 * fh;
                const int t = acc[i][j][reg] - zwi * rsx[row] + ccol;
                out[(size_t)row * GN + col] = fmaf(sxsw, (float)t, bv);
            }
        }
    }
}

// ---------- launch ----------
extern "C" void kernel_launch(void* const* d_in, const int* in_sizes, int n_in,
                              void* d_out, int out_size, void* d_ws, size_t ws_size,
                              hipStream_t stream) {
    const float* x    = (const float*)d_in[0];
    const float* Wt   = (const float*)d_in[1];
    const float* bias = (const float*)d_in[2];
    float* out = (float*)d_out;

    char* ws = (char*)d_ws;
    signed char* qx = (signed char*)(ws + QX_OFF);
    signed char* qw = (signed char*)(ws + QW_OFF);
    int* rsx = (int*)(ws + RSX_OFF);
    int* rsw = (int*)(ws + RSW_OFF);
    float* part = (float*)(ws + QX_OFF);   // 24 KB, consumed before qx is written
    float* prm = (float*)(ws + PRM_OFF);

    k_minmax<<<MMB_X + MMB_W, 256, 0, stream>>>((const float4*)x, (const float4*)Wt, part);
    k_params<<<1, 256, 0, stream>>>(part, prm);
    k_quant<<<(GM + GN) / 4, 256, 0, stream>>>(x, Wt, qx, qw, rsx, rsw, prm);
    k_gemm<<<(GM / 256) * (GN / 128), 256, 0, stream>>>(qx, qw, rsx, rsw, bias,
                                                        prm, out);
}

// Round 4
// 441.822 us; speedup vs baseline: 1.0214x; 1.0214x over previous
//
#include <hip/hip_runtime.h>

// Problem constants (fixed by the reference: B=4, S=2048, D_IN=D_OUT=4096)
#define GM 8192
#define GN 4096
#define GK 4096
#define NT (GK / 64)

// Workspace layout (bytes)
#define QX_OFF   0ull                      // int8 [8192][4096] = 33.5 MB; first 24 KB
                                           // doubles as minmax partials (consumed by
                                           // k_params BEFORE k_quant overwrites it)
#define QW_OFF   33554432ull               // int8 [4096][4096]  = 16.8 MB
#define RSX_OFF  50331648ull               // int32[8192]
#define RSW_OFF  50364416ull               // int32[4096]
#define PRM_OFF  50380832ull               // params: sx, zxf, sw, zwf, sxsw, zxi, zwi

#define MMB_X 2048                         // minmax blocks for x
#define MMB_W 1024                         // minmax blocks for W

using v4i  = __attribute__((ext_vector_type(4)))  int;
using v16i = __attribute__((ext_vector_type(16))) int;

// ---------- helpers ----------
__device__ __forceinline__ void async16(const signed char* g, signed char* l) {
    // 16B per lane, LDS dest = wave-uniform base + lane*16 (m104/m108 rule)
    __builtin_amdgcn_global_load_lds((const __attribute__((address_space(1))) void*)g,
                                     (__attribute__((address_space(3))) void*)l,
                                     16, 0, 0);
}

// ---------- kernels ----------
// Per-block partial min/max, plain stores (atomics removed in r1: -77 us).
// part[]: [0,2048) mx_x | [2048,4096) mn_x | [4096,5120) mx_w | [5120,6144) mn_w
__global__ void k_minmax(const float4* __restrict__ x, const float4* __restrict__ Wt,
                         float* __restrict__ part) {
    const float4* p; int n4, b0, nb; float* dst;
    if (blockIdx.x < MMB_X) { p = x;  n4 = GM * GK / 4; b0 = blockIdx.x;         nb = MMB_X; dst = part;        }
    else                    { p = Wt; n4 = GN * GK / 4; b0 = blockIdx.x - MMB_X; nb = MMB_W; dst = part + 4096; }
    float mx = -3.4e38f, mn = 3.4e38f;
    for (int i = b0 * 256 + threadIdx.x; i < n4; i += nb * 256) {
        float4 v = p[i];
        mx = fmaxf(mx, fmaxf(fmaxf(v.x, v.y), fmaxf(v.z, v.w)));
        mn = fminf(mn, fminf(fminf(v.x, v.y), fminf(v.z, v.w)));
    }
    #pragma unroll
    for (int o = 32; o > 0; o >>= 1) {
        mx = fmaxf(mx, __shfl_down(mx, o));
        mn = fminf(mn, __shfl_down(mn, o));
    }
    __shared__ float smx[4], smn[4];
    int w = threadIdx.x >> 6;
    if ((threadIdx.x & 63) == 0) { smx[w] = mx; smn[w] = mn; }
    __syncthreads();
    if (threadIdx.x == 0) {
        #pragma unroll
        for (int i = 1; i < 4; i++) { mx = fmaxf(mx, smx[i]); mn = fminf(mn, smn[i]); }
        dst[b0]      = mx;
        dst[nb + b0] = mn;
    }
}

// Reduce the 6144 partials (24 KB, L2-hot) and emit quant params. One block.
__global__ void k_params(const float* __restrict__ part, float* prm) {
    const int t = threadIdx.x;
    float v0 = -3.4e38f, v1 = 3.4e38f, v2 = -3.4e38f, v3 = 3.4e38f;
    for (int i = t; i < MMB_X; i += 256) {
        v0 = fmaxf(v0, part[i]);
        v1 = fminf(v1, part[MMB_X + i]);
    }
    for (int i = t; i < MMB_W; i += 256) {
        v2 = fmaxf(v2, part[4096 + i]);
        v3 = fminf(v3, part[5120 + i]);
    }
    #pragma unroll
    for (int o = 32; o > 0; o >>= 1) {
        v0 = fmaxf(v0, __shfl_down(v0, o));
        v1 = fminf(v1, __shfl_down(v1, o));
        v2 = fmaxf(v2, __shfl_down(v2, o));
        v3 = fminf(v3, __shfl_down(v3, o));
    }
    __shared__ float s[4][4];
    const int wv = t >> 6;
    if ((t & 63) == 0) { s[wv][0] = v0; s[wv][1] = v1; s[wv][2] = v2; s[wv][3] = v3; }
    __syncthreads();
    if (t == 0) {
        #pragma unroll
        for (int i = 1; i < 4; i++) {
            v0 = fmaxf(v0, s[i][0]); v1 = fminf(v1, s[i][1]);
            v2 = fmaxf(v2, s[i][2]); v3 = fminf(v3, s[i][3]);
        }
        float sx  = (v0 - v1) / 255.0f;
        float zxf = rintf(-128.0f - v1 / sx);
        float sw  = (v2 - v3) / 255.0f;
        float zwf = rintf(-128.0f - v3 / sw);
        prm[0] = sx; prm[1] = zxf; prm[2] = sw; prm[3] = zwf; prm[4] = sx * sw;
        int* ip = (int*)prm;
        ip[5] = (int)zxf; ip[6] = (int)zwf;
    }
}

// ONE WAVE per row of 4096 floats: no __syncthreads, no LDS reduce, 16
// independent float4 loads in flight per lane. Quant math exact-fp32-division
// to match JAX rounding. waves [0,GM) -> x rows; [GM, GM+GN) -> W rows.
__global__ void k_quant(const float* __restrict__ x, const float* __restrict__ Wt,
                        signed char* __restrict__ qx, signed char* __restrict__ qw,
                        int* __restrict__ rsx, int* __restrict__ rsw,
                        const float* __restrict__ prm) {
    const int wid  = (blockIdx.x << 2) | (threadIdx.x >> 6);   // global wave id
    const int lane = threadIdx.x & 63;
    const float* src; signed char* q; int* rs; int pidx, row;
    if (wid < GM) { row = wid;      src = x;  q = qx; rs = rsx; pidx = 0; }
    else          { row = wid - GM; src = Wt; q = qw; rs = rsw; pidx = 2; }
    const float s  = prm[pidx];
    const float zp = prm[pidx + 1];
    const float4* srow = (const float4*)(src + (size_t)row * GK);
    int* qrow = (int*)(q + (size_t)row * GK);
    int acc = 0;
    #pragma unroll
    for (int i = 0; i < 16; i++) {
        float4 v = srow[i * 64 + lane];
        int q0 = (int)fminf(fmaxf(rintf(v.x / s) + zp, -128.0f), 127.0f);
        int q1 = (int)fminf(fmaxf(rintf(v.y / s) + zp, -128.0f), 127.0f);
        int q2 = (int)fminf(fmaxf(rintf(v.z / s) + zp, -128.0f), 127.0f);
        int q3 = (int)fminf(fmaxf(rintf(v.w / s) + zp, -128.0f), 127.0f);
        acc += q0 + q1 + q2 + q3;
        qrow[i * 64 + lane] = (q0 & 255) | ((q1 & 255) << 8) | ((q2 & 255) << 16)
                            | ((q3 & 255) << 24);
    }
    #pragma unroll
    for (int o = 32; o > 0; o >>= 1) acc += __shfl_down(acc, o);
    if (lane == 0) rs[row] = acc;
}

// r1 geometry (256x256 tile, 512 thr = 8 waves 2Mx4N, BK=64, 3-buf LDS,
// counted vmcnt) + faithful m201 4-PHASE interleave. Per K-step, phase p:
//   {2 ds_read_b128 (A row p; P0 also 4 B reads) | 1 global_load_lds |
//    s_barrier | lgkmcnt(0) | setprio(1) 4 MFMA setprio(0) | s_barrier}
// vmcnt(4) once per K-step at P3 tail (each wave owns 4 loads/step; buf kt+1's
// loads retire exactly one barrier before their first read). NO sched_barrier
// (r2's m141-style poison), no fat read clusters (r2's m196 poison).
// Publish safety: all reads of a buffer are lgkm-complete before their phase's
// closing barrier; overwrites of that buffer issue only after that barrier.
__global__ __launch_bounds__(512, 2) void k_gemm(
    const signed char* __restrict__ qx, const signed char* __restrict__ qw,
    const int* __restrict__ rsx, const int* __restrict__ rsw,
    const float* __restrict__ bias, const float* __restrict__ prm,
    float* __restrict__ out) {
    __shared__ __align__(16) signed char lds[3][2][256 * 64];  // 96 KB -> 1 block/CU

    const int tid  = threadIdx.x;
    const int lane = tid & 63;
    const int w    = tid >> 6;          // 0..7
    // XCD swizzle (r1 mapping, bijective: 512 blocks % 8 == 0)
    const int bid  = ((blockIdx.x & 7) << 6) | (blockIdx.x >> 3);
    const int tm0  = (bid >> 4) * 256;  // 32 M-tiles
    const int tn0  = (bid & 15) * 256;  // 16 N-tiles

    // ---- staging: waves 0-3 -> A slab rows [w*64,+64); 4-7 -> B ----
    const int slab = w & 3;
    const int sr   = lane >> 2;                              // row 0..15 in 1KB segment
    const int sc   = ((lane & 3) ^ ((lane >> 3) & 3)) * 16;  // inverse-swizzled source chunk
    const signed char* gsrc = (w < 4)
        ? qx + (size_t)(tm0 + slab * 64 + sr) * GK + sc
        : qw + (size_t)(tn0 + slab * 64 + sr) * GK + sc;
    const int ldsTensor = (w < 4) ? 0 : 1;
    const int ldsSlab   = slab * 64 * 64;                    // byte offset of 64-row slab

    // ---- fragment / MFMA setup ----
    const int wr = w >> 2;              // 0..1 : wave row (M)
    const int wc = w & 3;               // 0..3 : wave col (N)
    const int fr = lane & 31;
    const int fh = lane >> 5;

    v16i acc[4][2] = {};

    // read-side swizzle offsets (chunk cc stored at cc ^ ((row>>1)&3))
    const int ca0 = ((fh    ) ^ ((fr >> 1) & 3)) * 16;  // k-chunk s=0 (cc = fh)
    const int ca1 = ((2 + fh) ^ ((fr >> 1) & 3)) * 16;  // k-chunk s=1 (cc = 2+fh)

    // prologue: stage kt=0 -> buf0, kt=1 -> buf1 (8 loads in flight per wave)
    #pragma unroll
    for (int j = 0; j < 4; j++)
        async16(gsrc + (size_t)j * 16 * GK, &lds[0][ldsTensor][ldsSlab + j * 1024]);
    #pragma unroll
    for (int j = 0; j < 4; j++)
        async16(gsrc + (size_t)j * 16 * GK + 64, &lds[1][ldsTensor][ldsSlab + j * 1024]);
    asm volatile("s_waitcnt vmcnt(4)" ::: "memory");   // buf0's 4 retired
    __builtin_amdgcn_s_barrier();                      // publish buf0

    int rd = 0;
    for (int kt = 0; kt < NT; ++kt) {
        int st = rd + 2; if (st >= 3) st -= 3;
        const size_t ko = (size_t)(kt + 2) * 64;
        const bool stg = (kt < NT - 2);
        const signed char* cA = lds[rd][0];
        const signed char* cB = lds[rd][1];
        v4i fb[2][2];                                   // [col j][chunk s]
        #pragma unroll
        for (int p = 0; p < 4; ++p) {
            // ---- phase p: ds reads ----
            const int ar = (wr * 128 + p * 32 + fr) * 64;
            v4i fa0 = *(const v4i*)(cA + ar + ca0);
            v4i fa1 = *(const v4i*)(cA + ar + ca1);
            if (p == 0) {
                const int br0 = (wc * 64      + fr) * 64;
                const int br1 = (wc * 64 + 32 + fr) * 64;
                fb[0][0] = *(const v4i*)(cB + br0 + ca0);
                fb[0][1] = *(const v4i*)(cB + br0 + ca1);
                fb[1][0] = *(const v4i*)(cB + br1 + ca0);
                fb[1][1] = *(const v4i*)(cB + br1 + ca1);
            }
            // ---- stage one 1KB segment of buf kt+2 ----
            if (stg)
                async16(gsrc + (size_t)p * 16 * GK + ko,
                        &lds[st][ldsTensor][ldsSlab + p * 1024]);
            __builtin_amdgcn_s_barrier();
            asm volatile("s_waitcnt lgkmcnt(0)" ::: "memory");
            __builtin_amdgcn_s_setprio(1);
            acc[p][0] = __builtin_amdgcn_mfma_i32_32x32x32_i8(fa0, fb[0][0], acc[p][0], 0, 0, 0);
            acc[p][1] = __builtin_amdgcn_mfma_i32_32x32x32_i8(fa0, fb[1][0], acc[p][1], 0, 0, 0);
            acc[p][0] = __builtin_amdgcn_mfma_i32_32x32x32_i8(fa1, fb[0][1], acc[p][0], 0, 0, 0);
            acc[p][1] = __builtin_amdgcn_mfma_i32_32x32x32_i8(fa1, fb[1][1], acc[p][1], 0, 0, 0);
            __builtin_amdgcn_s_setprio(0);
            if (p == 3) {                               // counted vmcnt, once per K-step
                if (stg)               asm volatile("s_waitcnt vmcnt(4)" ::: "memory");
                else if (kt == NT - 2) asm volatile("s_waitcnt vmcnt(0)" ::: "memory");
            }
            __builtin_amdgcn_s_barrier();               // P3: publishes buf kt+1
        }
        rd = (rd + 1 == 3) ? 0 : rd + 1;
    }

    // epilogue: acc - zw*rowsum_x[m] - zx*rowsum_w[n] + K*zx*zw, scale, +bias
    // 32x32 C/D: col = lane&31, row = (reg&3) + 8*(reg>>2) + 4*(lane>>5)
    const float sxsw = prm[4];
    const int* ip = (const int*)prm;
    const int zxi = ip[5], zwi = ip[6];
    const int kzz = GK * zxi * zwi;
    #pragma unroll
    for (int i = 0; i < 4; i++) {
        #pragma unroll
        for (int j = 0; j < 2; j++) {
            const int col = tn0 + wc * 64 + j * 32 + fr;
            const int ccol = kzz - zxi * rsw[col];
            const float bv = bias[col];
            #pragma unroll
            for (int reg = 0; reg < 16; reg++) {
                const int row = tm0 + wr * 128 + i * 32
                              + (reg & 3) + 8 * (reg >> 2) + 4 * fh;
                const int t = acc[i][j][reg] - zwi * rsx[row] + ccol;
                out[(size_t)row * GN + col] = fmaf(sxsw, (float)t, bv);
            }
        }
    }
}

// ---------- launch ----------
extern "C" void kernel_launch(void* const* d_in, const int* in_sizes, int n_in,
                              void* d_out, int out_size, void* d_ws, size_t ws_size,
                              hipStream_t stream) {
    const float* x    = (const float*)d_in[0];
    const float* Wt   = (const float*)d_in[1];
    const float* bias = (const float*)d_in[2];
    float* out = (float*)d_out;

    char* ws = (char*)d_ws;
    signed char* qx = (signed char*)(ws + QX_OFF);
    signed char* qw = (signed char*)(ws + QW_OFF);
    int* rsx = (int*)(ws + RSX_OFF);
    int* rsw = (int*)(ws + RSW_OFF);
    float* part = (float*)(ws + QX_OFF);   // 24 KB, consumed before qx is written
    float* prm = (float*)(ws + PRM_OFF);

    k_minmax<<<MMB_X + MMB_W, 256, 0, stream>>>((const float4*)x, (const float4*)Wt, part);
    k_params<<<1, 256, 0, stream>>>(part, prm);
    k_quant<<<(GM + GN) / 4, 256, 0, stream>>>(x, Wt, qx, qw, rsx, rsw, prm);
    k_gemm<<<(GM / 256) * (GN / 256), 512, 0, stream>>>(qx, qw, rsx, rsw, bias,
                                                        prm, out);
}